// Round 3
// baseline (273.121 us; speedup 1.0000x reference)
//
#include <hip/hip_runtime.h>
#include <stdint.h>

// ---------------------------------------------------------------------------
// SpecAugment (SpecaugmentModuleV1) — exact replication of JAX threefry RNG.
//
// Masks depend only on jax.random.key(42) => fully deterministic.
// PARTITIONABLE=1 replicates jax_threefry_partitionable=True (default since
// JAX 0.4.30). If the bench fails with absmax ~= max|input| (≈5.4), flip to 0
// for the legacy (original) threefry split / random_bits semantics.
// ---------------------------------------------------------------------------
#define PARTITIONABLE 1

struct Key { uint32_t x, y; };

#define TF_ROUND(x0, x1, r)                  \
  do {                                       \
    (x0) += (x1);                            \
    (x1) = ((x1) << (r)) | ((x1) >> (32 - (r))); \
    (x1) ^= (x0);                            \
  } while (0)

__host__ __device__ inline Key threefry_block(Key k, uint32_t c0, uint32_t c1) {
  uint32_t ks0 = k.x, ks1 = k.y, ks2 = k.x ^ k.y ^ 0x1BD11BDAu;
  uint32_t x0 = c0 + ks0;
  uint32_t x1 = c1 + ks1;
  // 20 rounds = 5 groups of 4, alternating rotation sets, key injections between
  TF_ROUND(x0, x1, 13); TF_ROUND(x0, x1, 15); TF_ROUND(x0, x1, 26); TF_ROUND(x0, x1, 6);
  x0 += ks1; x1 += ks2 + 1u;
  TF_ROUND(x0, x1, 17); TF_ROUND(x0, x1, 29); TF_ROUND(x0, x1, 16); TF_ROUND(x0, x1, 24);
  x0 += ks2; x1 += ks0 + 2u;
  TF_ROUND(x0, x1, 13); TF_ROUND(x0, x1, 15); TF_ROUND(x0, x1, 26); TF_ROUND(x0, x1, 6);
  x0 += ks0; x1 += ks1 + 3u;
  TF_ROUND(x0, x1, 17); TF_ROUND(x0, x1, 29); TF_ROUND(x0, x1, 16); TF_ROUND(x0, x1, 24);
  x0 += ks1; x1 += ks2 + 4u;
  TF_ROUND(x0, x1, 13); TF_ROUND(x0, x1, 15); TF_ROUND(x0, x1, 26); TF_ROUND(x0, x1, 6);
  x0 += ks2; x1 += ks0 + 5u;
  Key r; r.x = x0; r.y = x1;
  return r;
}

// random_bits(key, 32, shape) for flat index i, total size n.
__device__ inline uint32_t rand_bits(Key k, uint32_t i, uint32_t n) {
#if PARTITIONABLE
  (void)n;
  Key r = threefry_block(k, 0u, i);     // counts from 64-bit iota: (hi=0, lo=i)
  return r.x ^ r.y;                     // 32-bit path xors the two outputs
#else
  uint32_t odd = n & 1u;
  uint32_t h = (n + odd) >> 1;          // half size after optional zero-pad
  if (i < h) {
    uint32_t c1 = (odd && (i == h - 1u)) ? 0u : (h + i);
    return threefry_block(k, i, c1).x;
  } else {
    uint32_t j = i - h;
    return threefry_block(k, j, i).y;   // i == h + j < n always
  }
#endif
}

// jax.random.split(key, num) computed on host.
static void split_keys(Key k, int num, Key* out) {
#if PARTITIONABLE
  for (int i = 0; i < num; i++) out[i] = threefry_block(k, 0u, (uint32_t)i);
#else
  // counts = iota(2*num); x0 = counts[:num], x1 = counts[num:]
  uint32_t fl[16];
  for (int i = 0; i < num; i++) {
    Key r = threefry_block(k, (uint32_t)i, (uint32_t)(num + i));
    fl[i] = r.x;
    fl[num + i] = r.y;
  }
  for (int j = 0; j < num; j++) { out[j].x = fl[2 * j]; out[j].y = fl[2 * j + 1]; }
#endif
}

// randint offset in [0, span): JAX's double-draw remainder trick.
__device__ inline uint32_t randint_off(Key ka, Key kb, uint32_t idx, uint32_t n,
                                       uint32_t span) {
  uint32_t hi = rand_bits(ka, idx, n);
  uint32_t lo = rand_bits(kb, idx, n);
  uint32_t m = 65536u % span;           // 2^16 % span
  m = (m * m) % span;                   // 2^32 % span
  uint32_t off = (hi % span) * m + (lo % span);
  return off % span;
}

// ---------------------------------------------------------------------------
// Mask generation: one block per batch row. Replicates
//   num_masks = randint(k1, (B,), min, max)           [k1 split -> kna,knb]
//   z         = uniform(k2, (B, dim))
//   _, pos    = lax.top_k(z, M)        (ties -> lower index first)
//   amount    = randint(k3, (B, M), 1, max_len+1)     [k3 split -> kaa,kab]
//   cond[b,t] = any_m (m < num_masks) & (pos[m] <= t < min(pos[m]+amount[m], dim))
// ---------------------------------------------------------------------------
#define MAXM 19

__global__ __launch_bounds__(256) void specaug_mask_kernel(
    uint8_t* __restrict__ cond, int dim, int M, int span_num, int span_amt,
    Key kz, Key kna, Key knb, Key kaa, Key kab, int B) {
  __shared__ float z[3000];
  __shared__ float redv[4];
  __shared__ int redi[4];
  __shared__ int pos[MAXM];

  const int b = blockIdx.x;
  const int tid = threadIdx.x;
  const uint32_t n_z = (uint32_t)B * (uint32_t)dim;

  // z row: uniform [0,1): bitcast((bits>>9)|0x3f800000) - 1
  for (int t = tid; t < dim; t += 256) {
    uint32_t bits = rand_bits(kz, (uint32_t)(b * dim + t), n_z);
    z[t] = __uint_as_float((bits >> 9) | 0x3f800000u) - 1.0f;
  }
  __syncthreads();

  // top-M extraction, ties prefer lower index (XLA top_k semantics)
  for (int m = 0; m < M; m++) {
    float bv = -0.5f;          // valid z in [0,1); removed entries are -1.0
    int bi = 0x7fffffff;
    for (int t = tid; t < dim; t += 256) {
      float v = z[t];
      if (v > bv || (v == bv && t < bi)) { bv = v; bi = t; }
    }
    // 64-lane wave reduce
    for (int off = 32; off > 0; off >>= 1) {
      float ov = __shfl_down(bv, off);
      int oi = __shfl_down(bi, off);
      if (ov > bv || (ov == bv && oi < bi)) { bv = ov; bi = oi; }
    }
    if ((tid & 63) == 0) { redv[tid >> 6] = bv; redi[tid >> 6] = bi; }
    __syncthreads();
    if (tid == 0) {
      float Bv = redv[0]; int Bi = redi[0];
      for (int j = 1; j < 4; j++) {
        if (redv[j] > Bv || (redv[j] == Bv && redi[j] < Bi)) { Bv = redv[j]; Bi = redi[j]; }
      }
      pos[m] = Bi;
      z[Bi] = -1.0f;           // remove from further rounds
    }
    __syncthreads();
  }

  // zero this row's cond (d_ws is poisoned 0xAA before every launch)
  for (int t = tid; t < dim; t += 256) cond[b * dim + t] = 0;
  __syncthreads();

  if (tid == 0) {
    int nm = 1 + (int)randint_off(kna, knb, (uint32_t)b, (uint32_t)B, (uint32_t)span_num);
    int nmask = (nm < M) ? nm : M;
    for (int m = 0; m < nmask; m++) {
      int amt = 1 + (int)randint_off(kaa, kab, (uint32_t)(b * M + m),
                                     (uint32_t)(B * M), (uint32_t)span_amt);
      int p = pos[m];
      int p2 = p + amt;
      if (p2 > dim) p2 = dim;
      for (int t = p; t < p2; t++) cond[b * dim + t] = 1;
    }
  }
}

// ---------------------------------------------------------------------------
// Apply: out[b,t,f] = (tc[b,t] | fc[b,f]) ? 0 : in[b,t,f], float4-vectorized.
// F=80 is divisible by 4 so each float4 stays within one (b,t) row.
// ---------------------------------------------------------------------------
__global__ __launch_bounds__(256) void specaug_apply_kernel(
    const float4* __restrict__ in, float4* __restrict__ out,
    const uint8_t* __restrict__ tc, const uint8_t* __restrict__ fc, int nvec) {
  const int stride = gridDim.x * blockDim.x;
  for (int v = blockIdx.x * blockDim.x + threadIdx.x; v < nvec; v += stride) {
    int e = v << 2;            // element index
    int f = e % 80;            // multiple of 4
    int bt = e / 80;           // b*3000 + t
    int b = bt / 3000;
    float4 x = in[v];
    uint32_t tm = tc[bt];
    uchar4 fm = *reinterpret_cast<const uchar4*>(fc + b * 80 + f);
    float4 y;
    y.x = (tm | fm.x) ? 0.0f : x.x;
    y.y = (tm | fm.y) ? 0.0f : x.y;
    y.z = (tm | fm.z) ? 0.0f : x.z;
    y.w = (tm | fm.w) ? 0.0f : x.w;
    out[v] = y;
  }
}

extern "C" void kernel_launch(void* const* d_in, const int* in_sizes, int n_in,
                              void* d_out, int out_size, void* d_ws, size_t ws_size,
                              hipStream_t stream) {
  (void)in_sizes; (void)n_in; (void)out_size; (void)ws_size;

  const int B = 128, T = 3000, F = 80;
  const float* in = (const float*)d_in[0];
  float* out = (float*)d_out;
  uint8_t* tc = (uint8_t*)d_ws;          // [B][T] time cond
  uint8_t* fc = tc + (size_t)B * T;      // [B][F] freq cond

  // ---- host-side key tree (deterministic, same every call) ----
  Key root; root.x = 0u; root.y = 42u;   // jax.random.key(42) -> (0, 42)
  Key ktf[2]; split_keys(root, 2, ktf);  // kt, kf
  Key t123[3]; split_keys(ktf[0], 3, t123);  // time: k1, k2, k3
  Key f123[3]; split_keys(ktf[1], 3, f123);  // freq: k1, k2, k3
  Key tn[2]; split_keys(t123[0], 2, tn);     // randint(num, time) internal split
  Key ta[2]; split_keys(t123[2], 2, ta);     // randint(amount, time)
  Key fn[2]; split_keys(f123[0], 2, fn);     // randint(num, freq)
  Key fa[2]; split_keys(f123[2], 2, fa);     // randint(amount, freq)

  // time: min=1,max=20 -> M=19, span_num=19; len 1..20 -> span_amt=20
  specaug_mask_kernel<<<B, 256, 0, stream>>>(tc, T, 19, 19, 20,
                                             t123[1], tn[0], tn[1], ta[0], ta[1], B);
  // freq: min=1,max=5 -> M=4, span_num=4; len 1..16 -> span_amt=16
  specaug_mask_kernel<<<B, 256, 0, stream>>>(fc, F, 4, 4, 16,
                                             f123[1], fn[0], fn[1], fa[0], fa[1], B);

  const int nvec = B * T * F / 4;  // 7,680,000 float4
  specaug_apply_kernel<<<2048, 256, 0, stream>>>(
      (const float4*)in, (float4*)out, tc, fc, nvec);
}